// Round 10
// baseline (142.092 us; speedup 1.0000x reference)
//
#include <hip/hip_runtime.h>
#include <hip/hip_bf16.h>
#include <math.h>

#define LSEQ 2048
#define DMODEL 256
#define NH 8
#define HD 32

typedef __attribute__((ext_vector_type(8))) short bf16x8;
typedef __attribute__((ext_vector_type(4))) float f32x4;

#define MFMA __builtin_amdgcn_mfma_f32_16x16x32_bf16

__device__ __forceinline__ short f2bf(float x) {
  __hip_bfloat16 h = __float2bfloat16(x);
  return __builtin_bit_cast(short, h);
}
__device__ __forceinline__ float bf2f(short s) {
  __hip_bfloat16 h = __builtin_bit_cast(__hip_bfloat16, s);
  return __bfloat162float(h);
}
__device__ __forceinline__ short bftrunc(float x) {      // truncating f32->bf16
  return (short)(__builtin_bit_cast(unsigned int, x) >> 16);
}
// bare v_exp_f32 (2^x) — skip OCML denormal fixup (underflowed p contribute 0)
__device__ __forceinline__ float fexp2(float x) {
#if __has_builtin(__builtin_amdgcn_exp2f)
  return __builtin_amdgcn_exp2f(x);
#else
  return __expf(x * 0.6931471805599453f);
#endif
}
// pack trunc-bf16(lo), trunc-bf16(hi) into one u32 with a single v_perm_b32
__device__ __forceinline__ unsigned int packtrunc(float lo, float hi) {
  return __builtin_amdgcn_perm(__builtin_bit_cast(unsigned int, hi),
                               __builtin_bit_cast(unsigned int, lo),
                               0x07060302u);
}

// A/B fragment-major index for mfma_16x16x32: group = row/16, kc = col/32,
// lane = ((col>>3)&3)*16 + (row&15), elem = col&7.
// Linear element offset = ((group*8 + kc)*64 + lane)*8 + elem.

// ---- aux: x -> xf (A-frag), Wqkv -> Wf (B-frag), Wo -> Wof/Wolf (split
// B-frag), prior tables. Scatter paid ONCE here instead of 12-64x at the
// GEMM consumers (r6 lesson: 64-txn scattered wave loads dominated qkv/tail).
__global__ __launch_bounds__(256) void aux_kernel(
    const float* __restrict__ x,
    const float* __restrict__ Wq, const float* __restrict__ Wk,
    const float* __restrict__ Wv, const float* __restrict__ Wo,
    const float* __restrict__ u,
    short* __restrict__ xf,
    short* __restrict__ Wf,
    short* __restrict__ Wof, short* __restrict__ Wolf,
    float* __restrict__ Eb, float* __restrict__ Zb)
{
  __shared__ float Cs[LSEQ];
  __shared__ float part[256];
  const int tid = threadIdx.x;
  if (blockIdx.x < 1024) {            // x (4096x256 fp32) -> bf16 A-fragments
    const int i4 = (blockIdx.x * 256 + tid) * 4;
    const int row = i4 >> 8, col = i4 & 255;
    float4 v = *(const float4*)(x + i4);
    const size_t dst =
      ((((size_t)(row >> 4) * 8 + (col >> 5)) * 64) + ((col >> 3) & 3) * 16 + (row & 15)) * 8
      + (col & 7);
    *(short4*)(xf + dst) = make_short4(f2bf(v.x), f2bf(v.y), f2bf(v.z), f2bf(v.w));
    return;
  }
  const int bx = blockIdx.x - 1024;
  if (bx < 256) {
    const int i4 = (bx * 256 + tid) * 4;
    if (i4 < 196608) {                // Wq|Wk|Wv rows 0..767 -> B-fragments
      const int row = i4 >> 8, col = i4 & 255;
      const float* W = (row < 256) ? Wq : (row < 512) ? Wk : Wv;
      float4 v = *(const float4*)(W + (row & 255) * 256 + col);
      const size_t dst =
        ((((size_t)(row >> 4) * 8 + (col >> 5)) * 64) + ((col >> 3) & 3) * 16 + (row & 15)) * 8
        + (col & 7);
      *(short4*)(Wf + dst) = make_short4(f2bf(v.x), f2bf(v.y), f2bf(v.z), f2bf(v.w));
    } else {                          // Wo -> split bf16 B-fragments
      const int j = i4 - 196608;
      const int row = j >> 8, col = j & 255;
      float4 v = *(const float4*)(Wo + j);
      short h0 = f2bf(v.x), h1 = f2bf(v.y), h2 = f2bf(v.z), h3 = f2bf(v.w);
      const size_t dst =
        ((((size_t)(row >> 4) * 8 + (col >> 5)) * 64) + ((col >> 3) & 3) * 16 + (row & 15)) * 8
        + (col & 7);
      *(short4*)(Wof + dst) = make_short4(h0, h1, h2, h3);
      *(short4*)(Wolf + dst) = make_short4(bftrunc(v.x - bf2f(h0)), bftrunc(v.y - bf2f(h1)),
                                           bftrunc(v.z - bf2f(h2)), bftrunc(v.w - bf2f(h3)));
    }
    return;
  }
  const int h = bx - 256;
  const float uu = u[h];
  const float den = 2.0f * (uu * uu + 1e-6f);
  float e[8]; float run = 0.f;
  const int base = tid * 8;
#pragma unroll
  for (int j = 0; j < 8; ++j) {
    float d = (float)(base + j);
    e[j] = __expf(-(d * d) / den);
    run += e[j];
  }
  part[tid] = run;
  __syncthreads();
  for (int off = 1; off < 256; off <<= 1) {
    float v = (tid >= off) ? part[tid - off] : 0.f;
    __syncthreads();
    part[tid] += v;
    __syncthreads();
  }
  float c = part[tid] - run;
#pragma unroll
  for (int j = 0; j < 8; ++j) {
    c += e[j];
    Cs[base + j] = c;
    Eb[h * LSEQ + base + j] = e[j];
  }
  __syncthreads();
  const float E0 = Cs[0];
  for (int i = tid; i < LSEQ; i += 256) {
    float s = Cs[i] + Cs[LSEQ - 1 - i] - E0;
    Zb[h * LSEQ + i] = 1.0f / (s + 1e-6f);
  }
}

// ---------------- fused QKV GEMM (coalesced fragment loads) ------------------
__global__ __launch_bounds__(256) void qkv_gemm(
    const short* __restrict__ xf,
    const short* __restrict__ Wf,
    const float* __restrict__ bq, const float* __restrict__ bk,
    const float* __restrict__ bv,
    short* __restrict__ Qf, short* __restrict__ Kf, short* __restrict__ Vf)
{
  const int tid = threadIdx.x, w = tid >> 6, lane = tid & 63;
  const int l15 = lane & 15, q4 = lane >> 4;
  const int m0 = blockIdx.x * 64, n0 = blockIdx.y * 64;
  const bf16x8* xf8 = (const bf16x8*)xf;
  const bf16x8* wf8 = (const bf16x8*)Wf;
  const int mg8 = ((m0 >> 4) + w) * 8;
  f32x4 acc[4] = {{0,0,0,0},{0,0,0,0},{0,0,0,0},{0,0,0,0}};
  for (int kc = 0; kc < 8; ++kc) {
    bf16x8 ah = xf8[(mg8 + kc) * 64 + lane];
#pragma unroll
    for (int nt = 0; nt < 4; ++nt) {
      bf16x8 bh = wf8[(((n0 >> 4) + nt) * 8 + kc) * 64 + lane];
      acc[nt] = MFMA(ah, bh, acc[nt], 0, 0, 0);
    }
  }
  const int type = n0 >> 8;        // 0=Q 1=K 2=V
  const int n0l = n0 & 255;
  const float* bias = (type == 0) ? bq : (type == 1) ? bk : bv;
  const float qls = 0.25503489f;   // (1/sqrt(32)) * log2(e)
#pragma unroll
  for (int nt = 0; nt < 4; ++nt) {
    const int col = n0l + nt * 16 + l15;
    const float bvv = bias[col];
    const int hh = col >> 5, dloc = col & 31;
#pragma unroll
    for (int r = 0; r < 4; ++r) {
      const int m = m0 + w * 16 + q4 * 4 + r;
      float v = acc[nt][r] + bvv;
      const int bb = m >> 11, mm = m & 2047, rr = mm & 15;
      if (type == 2) {
        const int kt128 = mm >> 7, low7 = mm & 127;
        const int wv = (low7 >> 4) & 3, ph = low7 >> 6;
        // k-slot order c = rr*2+ph: pairs the two 16-col score halves
        // adjacently so attn's P-store is one ds_write_b32 (r9 change).
        const int c = rr * 2 + ph;
        const size_t idx =
          ((((((size_t)bb * 8 + hh) * 16 + kt128) * 4 + wv) * 2 + (dloc >> 4)) * 64
           + (c >> 3) * 16 + (dloc & 15)) * 8 + (c & 7);
        Vf[idx] = f2bf(v);
      } else if (type == 0) {
        const int qblk = mm >> 5, rg = (mm >> 4) & 1;
        const size_t idx =
          (((((size_t)bb * 8 + hh) * 64 + qblk) * 2 + rg) * 64
           + (dloc >> 3) * 16 + rr) * 8 + (dloc & 7);
        Qf[idx] = f2bf(v * qls);
      } else {
        const int g = mm >> 4;
        const size_t idx =
          ((((size_t)bb * 8 + hh) * 128 + g) * 64
           + (dloc >> 3) * 16 + rr) * 8 + (dloc & 7);
        Kf[idx] = f2bf(v);
      }
    }
  }
}

// ---------------- one-pass MFMA flash attention + deferred disc --------------
// r10: (a) p' cache moved from registers to LDS (Plds[16][4][16][17] dwords,
// 69.6KB; total ~71.5KB still fits 2 blocks/CU) — r9 showed the 16-reg pc
// cache spills to SCRATCH at the 32+acc VGPR allocation while dur is
// insensitive to the traffic; the real cost was zero registers left for ILP.
// (b) explicit 1-deep K/V prefetch with the freed registers: it+1's four 16B
// loads issue before it's compute, overlapping ~500cy global latency with
// MFMA+exp+LDS. Disc re-reads its own lane's packed dword (4 ds_read_b32/it,
// ~60cy) instead of scratch fills (~500cy). Numerics bit-identical to r9.
__global__ __launch_bounds__(1024, 8) void attn_kernel(
    const short* __restrict__ Qf, const short* __restrict__ Kf,
    const short* __restrict__ Vf,
    const float* __restrict__ Eb, const float* __restrict__ Zb,
    short* __restrict__ Ofb, short* __restrict__ Olfb,
    short* __restrict__ Dp)
{
  __shared__ unsigned int Plds[16][4][16][17];   // p' dwords (reused as Ored)
  __shared__ float Elds[192];
  __shared__ float lpart[16][16];
  __shared__ float lpn[16];         // 1/l per q-row
  __shared__ float liz[16];         // prior normalizer per q-row

  const int tid = threadIdx.x, w = tid >> 6, lane = tid & 63;
  const int l15 = lane & 15, q4 = lane >> 4;
  // ---- XCD swizzle: same (b,h) stays on one XCD ----
  const int flat = blockIdx.x + 128 * (blockIdx.y + 8 * blockIdx.z);
  const int slot = flat >> 3;                       // 0..255
  const int g = (flat & 7) | ((slot >> 7) << 3);    // 0..15
  const int h = g & 7, b = g >> 3;
  const int qslot = slot & 127, q0 = qslot * 16;
  const int bh = b * NH + h;

  if (tid < 192) Elds[tid] = Eb[h * LSEQ + tid];
  if (tid < 16)  liz[tid] = Zb[h * LSEQ + q0 + tid];

  const bf16x8* Qf8 = (const bf16x8*)Qf;
  const bf16x8* Kf8 = (const bf16x8*)Kf;
  const bf16x8* Vf8 = (const bf16x8*)Vf;

  bf16x8 qh = Qf8[((size_t)bh * 128 + qslot) * 64 + lane];

  const size_t kfb = (size_t)bh * 128;   // K 16-col-group base
  const size_t vfb = (size_t)bh * 16;    // V kt128 base
  const int wv = w & 3, wq = w >> 2;     // wave -> (16-col slot, kt128 base)

  float lac[4] = {0.f, 0.f, 0.f, 0.f};
  f32x4 oacc[2] = {{0,0,0,0},{0,0,0,0}};

  // ---- prefetch it=0 ----
  bf16x8 k0 = Kf8[(kfb + wq * 8 + wv) * 64 + lane];
  bf16x8 k1 = Kf8[(kfb + wq * 8 + wv + 4) * 64 + lane];
  bf16x8 vb0 = Vf8[(((vfb + wq) * 4 + wv) * 2 + 0) * 64 + lane];
  bf16x8 vb1 = Vf8[(((vfb + wq) * 4 + wv) * 2 + 1) * 64 + lane];

  // ---- single pass: QK^T -> p' -> {LDS dword store} -> PV, 1-deep prefetch --
#pragma unroll
  for (int it = 0; it < 4; ++it) {
    // issue next iteration's loads first ((it+1)&3 wraps: 4 redundant L2-hit
    // loads on the last iteration, avoids uninitialized temps)
    const int nk = wq + 4 * ((it + 1) & 3);
    bf16x8 nk0 = Kf8[(kfb + nk * 8 + wv) * 64 + lane];
    bf16x8 nk1 = Kf8[(kfb + nk * 8 + wv + 4) * 64 + lane];
    bf16x8 nv0 = Vf8[(((vfb + nk) * 4 + wv) * 2 + 0) * 64 + lane];
    bf16x8 nv1 = Vf8[(((vfb + nk) * 4 + wv) * 2 + 1) * 64 + lane];

    f32x4 s0 = {0.f,0.f,0.f,0.f}; s0 = MFMA(qh, k0, s0, 0, 0, 0);
    f32x4 s1 = {0.f,0.f,0.f,0.f}; s1 = MFMA(qh, k1, s1, 0, 0, 0);
#pragma unroll
    for (int r = 0; r < 4; ++r) {
      float p0 = fexp2(s0[r]);
      float p1 = fexp2(s1[r]);
      lac[r] += p0 + p1;
      // cols (2*l15, 2*l15+1) = k-slots (rr*2+0, rr*2+1) — matches V order
      Plds[w][it][q4 * 4 + r][l15] = packtrunc(p0, p1);
    }
    // wave-private: compiler inserts the lgkmcnt wait; wave-synchronous lanes
    // make the cross-lane write->read safe without a barrier (r2-proven).
    bf16x8 pa = *(const bf16x8*)&Plds[w][it][l15][q4 * 4];
    oacc[0] = MFMA(pa, vb0, oacc[0], 0, 0, 0);
    oacc[1] = MFMA(pa, vb1, oacc[1], 0, 0, 0);
    k0 = nk0; k1 = nk1; vb0 = nv0; vb1 = nv1;
  }

  // ---- l-reduce across 16 lanes then 16 waves ----
#pragma unroll
  for (int r = 0; r < 4; ++r) {
    float v = lac[r];
    v += __shfl_xor(v, 1); v += __shfl_xor(v, 2);
    v += __shfl_xor(v, 4); v += __shfl_xor(v, 8);
    if (l15 == 0) lpart[w][q4 * 4 + r] = v;
  }
  __syncthreads();
  if (tid < 16) {
    float l = 0.f;
#pragma unroll
    for (int w16 = 0; w16 < 16; ++w16) l += lpart[w16][tid];
    lpn[tid] = 1.0f / l;
  }
  __syncthreads();

  float pn4[4], iz4[4];
#pragma unroll
  for (int r = 0; r < 4; ++r) {
    pn4[r] = lpn[q4 * 4 + r];
    iz4[r] = liz[q4 * 4 + r];
  }
  const int qrow0 = q0 + q4 * 4;

  // ---- deferred disc: lane-local packed dwords re-read from LDS ----
  const size_t drow = (size_t)(g * 128 + qslot) * LSEQ;
#pragma unroll
  for (int it = 0; it < 4; ++it) {
    const int kt128 = wq + 4 * it;
    unsigned int pcv[4];
#pragma unroll
    for (int r = 0; r < 4; ++r) pcv[r] = Plds[w][it][q4 * 4 + r][l15];
#pragma unroll
    for (int ph = 0; ph < 2; ++ph) {
      const int c0g = kt128 * 128 + ph * 64 + wv * 16;
      const int kg = c0g + l15;
      const int dd = c0g - q0;
      const bool near = (dd >= -96) && (dd <= 96);
      float pr[4];
#pragma unroll
      for (int r = 0; r < 4; ++r)
        pr[r] = __builtin_bit_cast(float, ph ? (pcv[r] & 0xffff0000u)
                                             : (pcv[r] << 16));
      float dsum = 0.f;
      if (near) {
#pragma unroll
        for (int r = 0; r < 4; ++r) {
          float p = pr[r] * pn4[r];
          int qrow = qrow0 + r;
          int dist = (qrow >= kg) ? (qrow - kg) : (kg - qrow);
          dsum += fabsf(p - Elds[dist] * iz4[r]);
        }
      } else {
        dsum = pr[0] * pn4[0] + pr[1] * pn4[1] + pr[2] * pn4[2] + pr[3] * pn4[3];
      }
      dsum += __shfl_xor(dsum, 16);
      dsum += __shfl_xor(dsum, 32);
      if (q4 == 0) Dp[drow + kg] = f2bf(dsum);   // exactly-once per k
    }
  }

  // ---- epilogue: 16-wave O reduce, 1/l normalize, A-fragment-major store ----
  __syncthreads();
  float* Ored = (float*)Plds;   // [16*16][17] f32 = 17408 dwords, exact fit
  const size_t obase = ((size_t)(b * 128 + qslot) * 8 + h) * 64;
#pragma unroll
  for (int dt = 0; dt < 2; ++dt) {
#pragma unroll
    for (int r = 0; r < 4; ++r)
      Ored[(w * 16 + q4 * 4 + r) * 17 + l15] = oacc[dt][r];
    __syncthreads();
    if (tid < 256) {
      const int q = tid >> 4, d = tid & 15;
      float v = 0.f;
#pragma unroll
      for (int w16 = 0; w16 < 16; ++w16) v += Ored[(w16 * 16 + q) * 17 + d];
      v *= lpn[q];
      // fragment: row=q, col=h*32+dt*16+d -> kc=h, lane=((dt*16+d)>>3)*16+q
      const size_t oo = (obase + ((dt * 16 + d) >> 3) * 16 + q) * 8 + (d & 7);
      short hi = f2bf(v);
      Ofb[oo] = hi;
      Olfb[oo] = bftrunc(v - bf2f(hi));
    }
    __syncthreads();
  }
}

// ---------------- tail: output GEMM (512 blocks) + disc reduce (128) ---------
__global__ __launch_bounds__(256) void tail_kernel(
    const short* __restrict__ Ofb, const short* __restrict__ Olfb,
    const short* __restrict__ Wof, const short* __restrict__ Wolf,
    const float* __restrict__ bias, float* __restrict__ C,
    const short* __restrict__ Dp, float* __restrict__ disc)
{
  __shared__ float red[8][33];
  const int tid = threadIdx.x;
  if (blockIdx.x < 512) {
    const int w = tid >> 6, lane = tid & 63;
    const int l15 = lane & 15, q4 = lane >> 4;
    const int m0 = (blockIdx.x & 63) * 64, n0 = (blockIdx.x >> 6) * 32;
    const bf16x8* Ah8 = (const bf16x8*)Ofb;
    const bf16x8* Al8 = (const bf16x8*)Olfb;
    const bf16x8* Bh8 = (const bf16x8*)Wof;
    const bf16x8* Bl8 = (const bf16x8*)Wolf;
    const int mg8 = ((m0 >> 4) + w) * 8;
    f32x4 acc[2] = {{0,0,0,0},{0,0,0,0}};
    for (int kc = 0; kc < 8; ++kc) {
      bf16x8 ah = Ah8[(mg8 + kc) * 64 + lane];
      bf16x8 al = Al8[(mg8 + kc) * 64 + lane];
#pragma unroll
      for (int nt = 0; nt < 2; ++nt) {
        bf16x8 bh = Bh8[(((n0 >> 4) + nt) * 8 + kc) * 64 + lane];
        bf16x8 bl = Bl8[(((n0 >> 4) + nt) * 8 + kc) * 64 + lane];
        acc[nt] = MFMA(ah, bh, acc[nt], 0, 0, 0);
        acc[nt] = MFMA(al, bh, acc[nt], 0, 0, 0);
        acc[nt] = MFMA(ah, bl, acc[nt], 0, 0, 0);
      }
    }
#pragma unroll
    for (int nt = 0; nt < 2; ++nt) {
      const int col = n0 + nt * 16 + l15;
      const float bvv = bias[col];
#pragma unroll
      for (int r = 0; r < 4; ++r) {
        const int m = m0 + w * 16 + q4 * 4 + r;
        C[(size_t)m * 256 + col] = acc[nt][r] + bvv;
      }
    }
    return;
  }
  // ---- disc reduce: sum 1024 bf16 partial rows per batch ----
  const int bid = blockIdx.x - 512;
  const int b = bid >> 6, kb = (bid & 63) * 32;
  const int k = kb + (tid & 31), sg = tid >> 5;
  float acc = 0.f;
  const short* base = Dp + ((size_t)b * 1024 + (size_t)sg * 128) * LSEQ + k;
#pragma unroll 4
  for (int i = 0; i < 128; ++i) acc += bf2f(base[(size_t)i * LSEQ]);
  red[sg][tid & 31] = acc;
  __syncthreads();
  if (tid < 32) {
    float v = 0.f;
#pragma unroll
    for (int s2 = 0; s2 < 8; ++s2) v += red[s2][tid];
    disc[b * LSEQ + kb + tid] = v * (1.0f / ((float)NH * (float)LSEQ));
  }
}

extern "C" void kernel_launch(void* const* d_in, const int* in_sizes, int n_in,
                              void* d_out, int out_size, void* d_ws, size_t ws_size,
                              hipStream_t stream)
{
  const float* x  = (const float*)d_in[0];
  const float* Wq = (const float*)d_in[1];
  const float* bq = (const float*)d_in[2];
  const float* Wk = (const float*)d_in[3];
  const float* bk = (const float*)d_in[4];
  const float* Wv = (const float*)d_in[5];
  const float* bv = (const float*)d_in[6];
  const float* u  = (const float*)d_in[7];
  const float* Wo = (const float*)d_in[8];
  const float* bo = (const float*)d_in[9];

  float* out  = (float*)d_out;
  float* disc = out + (size_t)2 * LSEQ * DMODEL;

  char* w8 = (char*)d_ws;
  const size_t MB = 1u << 20;
  short* Qfb  = (short*)(w8);               // 2MB each
  short* Kfb  = (short*)(w8 + 2 * MB);
  short* Vfb  = (short*)(w8 + 4 * MB);
  short* Ofb  = (short*)(w8 + 6 * MB);
  short* Olfb = (short*)(w8 + 8 * MB);
  short* Wf   = (short*)(w8 + 10 * MB);                 // 384KB (Wqkv B-frag)
  short* Wof  = (short*)(w8 + 10 * MB + 393216);        // 128KB
  short* Wolf = (short*)(w8 + 10 * MB + 524288);        // 128KB
  float* Eb   = (float*)(w8 + 11 * MB);                 // 64KB
  float* Zb   = (float*)(w8 + 11 * MB + 65536);         // 64KB
  short* xf   = (short*)(w8 + 12 * MB);                 // 2MB (x A-frag)
  short* Dp   = (short*)(w8 + 14 * MB);                 // 8MB disc partials

  aux_kernel<<<1288, 256, 0, stream>>>(x, Wq, Wk, Wv, Wo, u, xf, Wf, Wof, Wolf, Eb, Zb);
  qkv_gemm<<<dim3(64, 12), 256, 0, stream>>>(xf, Wf, bq, bk, bv, Qfb, Kfb, Vfb);
  attn_kernel<<<dim3(128, 8, 2), 1024, 0, stream>>>(Qfb, Kfb, Vfb, Eb, Zb,
                                                    Ofb, Olfb, Dp);
  tail_kernel<<<640, 256, 0, stream>>>(Ofb, Olfb, Wof, Wolf, bo, out, Dp, disc);
}

// Round 11
// 139.459 us; speedup vs baseline: 1.0189x; 1.0189x over previous
//
#include <hip/hip_runtime.h>
#include <hip/hip_bf16.h>
#include <math.h>

#define LSEQ 2048
#define DMODEL 256
#define NH 8
#define HD 32

typedef __attribute__((ext_vector_type(8))) short bf16x8;
typedef __attribute__((ext_vector_type(4))) float f32x4;

#define MFMA __builtin_amdgcn_mfma_f32_16x16x32_bf16

__device__ __forceinline__ short f2bf(float x) {
  __hip_bfloat16 h = __float2bfloat16(x);
  return __builtin_bit_cast(short, h);
}
__device__ __forceinline__ float bf2f(short s) {
  __hip_bfloat16 h = __builtin_bit_cast(__hip_bfloat16, s);
  return __bfloat162float(h);
}
__device__ __forceinline__ short bftrunc(float x) {      // truncating f32->bf16
  return (short)(__builtin_bit_cast(unsigned int, x) >> 16);
}
// bare v_exp_f32 (2^x) — skip OCML denormal fixup (underflowed p contribute 0)
__device__ __forceinline__ float fexp2(float x) {
#if __has_builtin(__builtin_amdgcn_exp2f)
  return __builtin_amdgcn_exp2f(x);
#else
  return __expf(x * 0.6931471805599453f);
#endif
}
// pack trunc-bf16(lo), trunc-bf16(hi) into one u32 with a single v_perm_b32
__device__ __forceinline__ unsigned int packtrunc(float lo, float hi) {
  return __builtin_amdgcn_perm(__builtin_bit_cast(unsigned int, hi),
                               __builtin_bit_cast(unsigned int, lo),
                               0x07060302u);
}

// A/B fragment-major index for mfma_16x16x32: group = row/16, kc = col/32,
// lane = ((col>>3)&3)*16 + (row&15), elem = col&7.
// Linear element offset = ((group*8 + kc)*64 + lane)*8 + elem.

// ---- aux: x -> xf (A-frag), Wqkv -> Wf (B-frag), Wo -> Wof/Wolf (split
// B-frag), prior tables. Scatter paid ONCE here instead of 12-64x at the
// GEMM consumers (r6 lesson: 64-txn scattered wave loads dominated qkv/tail).
__global__ __launch_bounds__(256) void aux_kernel(
    const float* __restrict__ x,
    const float* __restrict__ Wq, const float* __restrict__ Wk,
    const float* __restrict__ Wv, const float* __restrict__ Wo,
    const float* __restrict__ u,
    short* __restrict__ xf,
    short* __restrict__ Wf,
    short* __restrict__ Wof, short* __restrict__ Wolf,
    float* __restrict__ Eb, float* __restrict__ Zb)
{
  __shared__ float Cs[LSEQ];
  __shared__ float part[256];
  const int tid = threadIdx.x;
  if (blockIdx.x < 1024) {            // x (4096x256 fp32) -> bf16 A-fragments
    const int i4 = (blockIdx.x * 256 + tid) * 4;
    const int row = i4 >> 8, col = i4 & 255;
    float4 v = *(const float4*)(x + i4);
    const size_t dst =
      ((((size_t)(row >> 4) * 8 + (col >> 5)) * 64) + ((col >> 3) & 3) * 16 + (row & 15)) * 8
      + (col & 7);
    *(short4*)(xf + dst) = make_short4(f2bf(v.x), f2bf(v.y), f2bf(v.z), f2bf(v.w));
    return;
  }
  const int bx = blockIdx.x - 1024;
  if (bx < 256) {
    const int i4 = (bx * 256 + tid) * 4;
    if (i4 < 196608) {                // Wq|Wk|Wv rows 0..767 -> B-fragments
      const int row = i4 >> 8, col = i4 & 255;
      const float* W = (row < 256) ? Wq : (row < 512) ? Wk : Wv;
      float4 v = *(const float4*)(W + (row & 255) * 256 + col);
      const size_t dst =
        ((((size_t)(row >> 4) * 8 + (col >> 5)) * 64) + ((col >> 3) & 3) * 16 + (row & 15)) * 8
        + (col & 7);
      *(short4*)(Wf + dst) = make_short4(f2bf(v.x), f2bf(v.y), f2bf(v.z), f2bf(v.w));
    } else {                          // Wo -> split bf16 B-fragments
      const int j = i4 - 196608;
      const int row = j >> 8, col = j & 255;
      float4 v = *(const float4*)(Wo + j);
      short h0 = f2bf(v.x), h1 = f2bf(v.y), h2 = f2bf(v.z), h3 = f2bf(v.w);
      const size_t dst =
        ((((size_t)(row >> 4) * 8 + (col >> 5)) * 64) + ((col >> 3) & 3) * 16 + (row & 15)) * 8
        + (col & 7);
      *(short4*)(Wof + dst) = make_short4(h0, h1, h2, h3);
      *(short4*)(Wolf + dst) = make_short4(bftrunc(v.x - bf2f(h0)), bftrunc(v.y - bf2f(h1)),
                                           bftrunc(v.z - bf2f(h2)), bftrunc(v.w - bf2f(h3)));
    }
    return;
  }
  const int h = bx - 256;
  const float uu = u[h];
  const float den = 2.0f * (uu * uu + 1e-6f);
  float e[8]; float run = 0.f;
  const int base = tid * 8;
#pragma unroll
  for (int j = 0; j < 8; ++j) {
    float d = (float)(base + j);
    e[j] = __expf(-(d * d) / den);
    run += e[j];
  }
  part[tid] = run;
  __syncthreads();
  for (int off = 1; off < 256; off <<= 1) {
    float v = (tid >= off) ? part[tid - off] : 0.f;
    __syncthreads();
    part[tid] += v;
    __syncthreads();
  }
  float c = part[tid] - run;
#pragma unroll
  for (int j = 0; j < 8; ++j) {
    c += e[j];
    Cs[base + j] = c;
    Eb[h * LSEQ + base + j] = e[j];
  }
  __syncthreads();
  const float E0 = Cs[0];
  for (int i = tid; i < LSEQ; i += 256) {
    float s = Cs[i] + Cs[LSEQ - 1 - i] - E0;
    Zb[h * LSEQ + i] = 1.0f / (s + 1e-6f);
  }
}

// ---------------- fused QKV GEMM (coalesced fragment loads) ------------------
__global__ __launch_bounds__(256) void qkv_gemm(
    const short* __restrict__ xf,
    const short* __restrict__ Wf,
    const float* __restrict__ bq, const float* __restrict__ bk,
    const float* __restrict__ bv,
    short* __restrict__ Qf, short* __restrict__ Kf, short* __restrict__ Vf)
{
  const int tid = threadIdx.x, w = tid >> 6, lane = tid & 63;
  const int l15 = lane & 15, q4 = lane >> 4;
  const int m0 = blockIdx.x * 64, n0 = blockIdx.y * 64;
  const bf16x8* xf8 = (const bf16x8*)xf;
  const bf16x8* wf8 = (const bf16x8*)Wf;
  const int mg8 = ((m0 >> 4) + w) * 8;
  f32x4 acc[4] = {{0,0,0,0},{0,0,0,0},{0,0,0,0},{0,0,0,0}};
  for (int kc = 0; kc < 8; ++kc) {
    bf16x8 ah = xf8[(mg8 + kc) * 64 + lane];
#pragma unroll
    for (int nt = 0; nt < 4; ++nt) {
      bf16x8 bh = wf8[(((n0 >> 4) + nt) * 8 + kc) * 64 + lane];
      acc[nt] = MFMA(ah, bh, acc[nt], 0, 0, 0);
    }
  }
  const int type = n0 >> 8;        // 0=Q 1=K 2=V
  const int n0l = n0 & 255;
  const float* bias = (type == 0) ? bq : (type == 1) ? bk : bv;
  const float qls = 0.25503489f;   // (1/sqrt(32)) * log2(e)
#pragma unroll
  for (int nt = 0; nt < 4; ++nt) {
    const int col = n0l + nt * 16 + l15;
    const float bvv = bias[col];
    const int hh = col >> 5, dloc = col & 31;
#pragma unroll
    for (int r = 0; r < 4; ++r) {
      const int m = m0 + w * 16 + q4 * 4 + r;
      float v = acc[nt][r] + bvv;
      const int bb = m >> 11, mm = m & 2047, rr = mm & 15;
      if (type == 2) {
        const int kt128 = mm >> 7, low7 = mm & 127;
        const int wv = (low7 >> 4) & 3, ph = low7 >> 6;
        // k-slot order c = rr*2+ph: pairs the two 16-col score halves
        // adjacently so attn's P-store is one ds_write_b32 (r9 change).
        const int c = rr * 2 + ph;
        const size_t idx =
          ((((((size_t)bb * 8 + hh) * 16 + kt128) * 4 + wv) * 2 + (dloc >> 4)) * 64
           + (c >> 3) * 16 + (dloc & 15)) * 8 + (c & 7);
        Vf[idx] = f2bf(v);
      } else if (type == 0) {
        const int qblk = mm >> 5, rg = (mm >> 4) & 1;
        const size_t idx =
          (((((size_t)bb * 8 + hh) * 64 + qblk) * 2 + rg) * 64
           + (dloc >> 3) * 16 + rr) * 8 + (dloc & 7);
        Qf[idx] = f2bf(v * qls);
      } else {
        const int g = mm >> 4;
        const size_t idx =
          ((((size_t)bb * 8 + hh) * 128 + g) * 64
           + (dloc >> 3) * 16 + rr) * 8 + (dloc & 7);
        Kf[idx] = f2bf(v);
      }
    }
  }
}

// ---------------- one-pass MFMA flash attention + deferred disc --------------
// r11: PHASE-SPLIT. Plds retains all 4 iterations' P tiles, so the QK and PV
// halves are fully decoupled: phase 1 = 4x {K load, QK MFMA, exp, pack, LDS
// write} (8 independent MFMA->exp chains, compiler-interleavable); phase 2 =
// 4x {V load, P read, 2 PV MFMA} (pure load+MFMA, 4-deep independent). No
// ds_read ever waits on a same-iteration exp (r10's residual serial chain).
// K regs live only in phase 1, V regs only in phase 2 -> lower peak pressure;
// r10's manual prefetch dropped (full unroll lets the scheduler hoist).
// Numerics bit-identical to r10.
__global__ __launch_bounds__(1024, 8) void attn_kernel(
    const short* __restrict__ Qf, const short* __restrict__ Kf,
    const short* __restrict__ Vf,
    const float* __restrict__ Eb, const float* __restrict__ Zb,
    short* __restrict__ Ofb, short* __restrict__ Olfb,
    short* __restrict__ Dp)
{
  __shared__ unsigned int Plds[16][4][16][17];   // p' dwords (reused as Ored)
  __shared__ float Elds[192];
  __shared__ float lpart[16][16];
  __shared__ float lpn[16];         // 1/l per q-row
  __shared__ float liz[16];         // prior normalizer per q-row

  const int tid = threadIdx.x, w = tid >> 6, lane = tid & 63;
  const int l15 = lane & 15, q4 = lane >> 4;
  // ---- XCD swizzle: same (b,h) stays on one XCD ----
  const int flat = blockIdx.x + 128 * (blockIdx.y + 8 * blockIdx.z);
  const int slot = flat >> 3;                       // 0..255
  const int g = (flat & 7) | ((slot >> 7) << 3);    // 0..15
  const int h = g & 7, b = g >> 3;
  const int qslot = slot & 127, q0 = qslot * 16;
  const int bh = b * NH + h;

  if (tid < 192) Elds[tid] = Eb[h * LSEQ + tid];
  if (tid < 16)  liz[tid] = Zb[h * LSEQ + q0 + tid];

  const bf16x8* Qf8 = (const bf16x8*)Qf;
  const bf16x8* Kf8 = (const bf16x8*)Kf;
  const bf16x8* Vf8 = (const bf16x8*)Vf;

  bf16x8 qh = Qf8[((size_t)bh * 128 + qslot) * 64 + lane];

  const size_t kfb = (size_t)bh * 128;   // K 16-col-group base
  const size_t vfb = (size_t)bh * 16;    // V kt128 base
  const int wv = w & 3, wq = w >> 2;     // wave -> (16-col slot, kt128 base)

  float lac[4] = {0.f, 0.f, 0.f, 0.f};
  f32x4 oacc[2] = {{0,0,0,0},{0,0,0,0}};

  // ---- phase 1: QK^T -> p' -> LDS (all 4 its, independent chains) ----
#pragma unroll
  for (int it = 0; it < 4; ++it) {
    const int gk = (wq + 4 * it) * 8 + wv;
    bf16x8 k0 = Kf8[(kfb + gk) * 64 + lane];
    bf16x8 k1 = Kf8[(kfb + gk + 4) * 64 + lane];
    f32x4 s0 = {0.f,0.f,0.f,0.f}; s0 = MFMA(qh, k0, s0, 0, 0, 0);
    f32x4 s1 = {0.f,0.f,0.f,0.f}; s1 = MFMA(qh, k1, s1, 0, 0, 0);
#pragma unroll
    for (int r = 0; r < 4; ++r) {
      float p0 = fexp2(s0[r]);
      float p1 = fexp2(s1[r]);
      lac[r] += p0 + p1;
      // cols (2*l15, 2*l15+1) = k-slots (rr*2+0, rr*2+1) — matches V order
      Plds[w][it][q4 * 4 + r][l15] = packtrunc(p0, p1);
    }
  }

  // ---- phase 2: PV from LDS (pure load + MFMA; no exp dependency) ----
  // wave-private: compiler inserts the lgkmcnt wait; wave-synchronous lanes
  // make the cross-lane write->read safe without a barrier (r2-proven).
#pragma unroll
  for (int it = 0; it < 4; ++it) {
    const int kt128 = wq + 4 * it;
    bf16x8 vb0 = Vf8[(((vfb + kt128) * 4 + wv) * 2 + 0) * 64 + lane];
    bf16x8 vb1 = Vf8[(((vfb + kt128) * 4 + wv) * 2 + 1) * 64 + lane];
    bf16x8 pa = *(const bf16x8*)&Plds[w][it][l15][q4 * 4];
    oacc[0] = MFMA(pa, vb0, oacc[0], 0, 0, 0);
    oacc[1] = MFMA(pa, vb1, oacc[1], 0, 0, 0);
  }

  // ---- l-reduce across 16 lanes then 16 waves ----
#pragma unroll
  for (int r = 0; r < 4; ++r) {
    float v = lac[r];
    v += __shfl_xor(v, 1); v += __shfl_xor(v, 2);
    v += __shfl_xor(v, 4); v += __shfl_xor(v, 8);
    if (l15 == 0) lpart[w][q4 * 4 + r] = v;
  }
  __syncthreads();
  if (tid < 16) {
    float l = 0.f;
#pragma unroll
    for (int w16 = 0; w16 < 16; ++w16) l += lpart[w16][tid];
    lpn[tid] = 1.0f / l;
  }
  __syncthreads();

  float pn4[4], iz4[4];
#pragma unroll
  for (int r = 0; r < 4; ++r) {
    pn4[r] = lpn[q4 * 4 + r];
    iz4[r] = liz[q4 * 4 + r];
  }
  const int qrow0 = q0 + q4 * 4;

  // ---- deferred disc: lane-local packed dwords re-read from LDS ----
  const size_t drow = (size_t)(g * 128 + qslot) * LSEQ;
#pragma unroll
  for (int it = 0; it < 4; ++it) {
    const int kt128 = wq + 4 * it;
    unsigned int pcv[4];
#pragma unroll
    for (int r = 0; r < 4; ++r) pcv[r] = Plds[w][it][q4 * 4 + r][l15];
#pragma unroll
    for (int ph = 0; ph < 2; ++ph) {
      const int c0g = kt128 * 128 + ph * 64 + wv * 16;
      const int kg = c0g + l15;
      const int dd = c0g - q0;
      const bool near = (dd >= -96) && (dd <= 96);
      float pr[4];
#pragma unroll
      for (int r = 0; r < 4; ++r)
        pr[r] = __builtin_bit_cast(float, ph ? (pcv[r] & 0xffff0000u)
                                             : (pcv[r] << 16));
      float dsum = 0.f;
      if (near) {
#pragma unroll
        for (int r = 0; r < 4; ++r) {
          float p = pr[r] * pn4[r];
          int qrow = qrow0 + r;
          int dist = (qrow >= kg) ? (qrow - kg) : (kg - qrow);
          dsum += fabsf(p - Elds[dist] * iz4[r]);
        }
      } else {
        dsum = pr[0] * pn4[0] + pr[1] * pn4[1] + pr[2] * pn4[2] + pr[3] * pn4[3];
      }
      dsum += __shfl_xor(dsum, 16);
      dsum += __shfl_xor(dsum, 32);
      if (q4 == 0) Dp[drow + kg] = f2bf(dsum);   // exactly-once per k
    }
  }

  // ---- epilogue: 16-wave O reduce, 1/l normalize, A-fragment-major store ----
  __syncthreads();
  float* Ored = (float*)Plds;   // [16*16][17] f32 = 17408 dwords, exact fit
  const size_t obase = ((size_t)(b * 128 + qslot) * 8 + h) * 64;
#pragma unroll
  for (int dt = 0; dt < 2; ++dt) {
#pragma unroll
    for (int r = 0; r < 4; ++r)
      Ored[(w * 16 + q4 * 4 + r) * 17 + l15] = oacc[dt][r];
    __syncthreads();
    if (tid < 256) {
      const int q = tid >> 4, d = tid & 15;
      float v = 0.f;
#pragma unroll
      for (int w16 = 0; w16 < 16; ++w16) v += Ored[(w16 * 16 + q) * 17 + d];
      v *= lpn[q];
      // fragment: row=q, col=h*32+dt*16+d -> kc=h, lane=((dt*16+d)>>3)*16+q
      const size_t oo = (obase + ((dt * 16 + d) >> 3) * 16 + q) * 8 + (d & 7);
      short hi = f2bf(v);
      Ofb[oo] = hi;
      Olfb[oo] = bftrunc(v - bf2f(hi));
    }
    __syncthreads();
  }
}

// ---------------- tail: output GEMM (512 blocks) + disc reduce (128) ---------
__global__ __launch_bounds__(256) void tail_kernel(
    const short* __restrict__ Ofb, const short* __restrict__ Olfb,
    const short* __restrict__ Wof, const short* __restrict__ Wolf,
    const float* __restrict__ bias, float* __restrict__ C,
    const short* __restrict__ Dp, float* __restrict__ disc)
{
  __shared__ float red[8][33];
  const int tid = threadIdx.x;
  if (blockIdx.x < 512) {
    const int w = tid >> 6, lane = tid & 63;
    const int l15 = lane & 15, q4 = lane >> 4;
    const int m0 = (blockIdx.x & 63) * 64, n0 = (blockIdx.x >> 6) * 32;
    const bf16x8* Ah8 = (const bf16x8*)Ofb;
    const bf16x8* Al8 = (const bf16x8*)Olfb;
    const bf16x8* Bh8 = (const bf16x8*)Wof;
    const bf16x8* Bl8 = (const bf16x8*)Wolf;
    const int mg8 = ((m0 >> 4) + w) * 8;
    f32x4 acc[2] = {{0,0,0,0},{0,0,0,0}};
    for (int kc = 0; kc < 8; ++kc) {
      bf16x8 ah = Ah8[(mg8 + kc) * 64 + lane];
      bf16x8 al = Al8[(mg8 + kc) * 64 + lane];
#pragma unroll
      for (int nt = 0; nt < 2; ++nt) {
        bf16x8 bh = Bh8[(((n0 >> 4) + nt) * 8 + kc) * 64 + lane];
        bf16x8 bl = Bl8[(((n0 >> 4) + nt) * 8 + kc) * 64 + lane];
        acc[nt] = MFMA(ah, bh, acc[nt], 0, 0, 0);
        acc[nt] = MFMA(al, bh, acc[nt], 0, 0, 0);
        acc[nt] = MFMA(ah, bl, acc[nt], 0, 0, 0);
      }
    }
#pragma unroll
    for (int nt = 0; nt < 2; ++nt) {
      const int col = n0 + nt * 16 + l15;
      const float bvv = bias[col];
#pragma unroll
      for (int r = 0; r < 4; ++r) {
        const int m = m0 + w * 16 + q4 * 4 + r;
        C[(size_t)m * 256 + col] = acc[nt][r] + bvv;
      }
    }
    return;
  }
  // ---- disc reduce: sum 1024 bf16 partial rows per batch ----
  const int bid = blockIdx.x - 512;
  const int b = bid >> 6, kb = (bid & 63) * 32;
  const int k = kb + (tid & 31), sg = tid >> 5;
  float acc = 0.f;
  const short* base = Dp + ((size_t)b * 1024 + (size_t)sg * 128) * LSEQ + k;
#pragma unroll 4
  for (int i = 0; i < 128; ++i) acc += bf2f(base[(size_t)i * LSEQ]);
  red[sg][tid & 31] = acc;
  __syncthreads();
  if (tid < 32) {
    float v = 0.f;
#pragma unroll
    for (int s2 = 0; s2 < 8; ++s2) v += red[s2][tid];
    disc[b * LSEQ + kb + tid] = v * (1.0f / ((float)NH * (float)LSEQ));
  }
}

extern "C" void kernel_launch(void* const* d_in, const int* in_sizes, int n_in,
                              void* d_out, int out_size, void* d_ws, size_t ws_size,
                              hipStream_t stream)
{
  const float* x  = (const float*)d_in[0];
  const float* Wq = (const float*)d_in[1];
  const float* bq = (const float*)d_in[2];
  const float* Wk = (const float*)d_in[3];
  const float* bk = (const float*)d_in[4];
  const float* Wv = (const float*)d_in[5];
  const float* bv = (const float*)d_in[6];
  const float* u  = (const float*)d_in[7];
  const float* Wo = (const float*)d_in[8];
  const float* bo = (const float*)d_in[9];

  float* out  = (float*)d_out;
  float* disc = out + (size_t)2 * LSEQ * DMODEL;

  char* w8 = (char*)d_ws;
  const size_t MB = 1u << 20;
  short* Qfb  = (short*)(w8);               // 2MB each
  short* Kfb  = (short*)(w8 + 2 * MB);
  short* Vfb  = (short*)(w8 + 4 * MB);
  short* Ofb  = (short*)(w8 + 6 * MB);
  short* Olfb = (short*)(w8 + 8 * MB);
  short* Wf   = (short*)(w8 + 10 * MB);                 // 384KB (Wqkv B-frag)
  short* Wof  = (short*)(w8 + 10 * MB + 393216);        // 128KB
  short* Wolf = (short*)(w8 + 10 * MB + 524288);        // 128KB
  float* Eb   = (float*)(w8 + 11 * MB);                 // 64KB
  float* Zb   = (float*)(w8 + 11 * MB + 65536);         // 64KB
  short* xf   = (short*)(w8 + 12 * MB);                 // 2MB (x A-frag)
  short* Dp   = (short*)(w8 + 14 * MB);                 // 8MB disc partials

  aux_kernel<<<1288, 256, 0, stream>>>(x, Wq, Wk, Wv, Wo, u, xf, Wf, Wof, Wolf, Eb, Zb);
  qkv_gemm<<<dim3(64, 12), 256, 0, stream>>>(xf, Wf, bq, bk, bv, Qfb, Kfb, Vfb);
  attn_kernel<<<dim3(128, 8, 2), 1024, 0, stream>>>(Qfb, Kfb, Vfb, Eb, Zb,
                                                    Ofb, Olfb, Dp);
  tail_kernel<<<640, 256, 0, stream>>>(Ofb, Olfb, Wof, Wolf, bo, out, Dp, disc);
}